// Round 7
// baseline (135.694 us; speedup 1.0000x reference)
//
#include <hip/hip_runtime.h>
#include <hip/hip_bf16.h>
#include <cstdint>
#include <cstddef>

using bf16 = __hip_bfloat16;
typedef __attribute__((ext_vector_type(8))) short bf16x8v;
typedef __attribute__((ext_vector_type(4))) float f32x4v;
typedef __attribute__((ext_vector_type(16))) float f32x16v;
typedef __attribute__((ext_vector_type(4))) int i32x4v;

__device__ __forceinline__ f32x4v mfma16x16x32(bf16x8v a, bf16x8v b, f32x4v c) {
  return __builtin_amdgcn_mfma_f32_16x16x32_bf16(a, b, c, 0, 0, 0);
}
__device__ __forceinline__ f32x16v mfma32x32x16(bf16x8v a, bf16x8v b, f32x16v c) {
  return __builtin_amdgcn_mfma_f32_32x32x16_bf16(a, b, c, 0, 0, 0);
}

__device__ __forceinline__ void lds_async16(const void* g, void* l) {
  __builtin_amdgcn_global_load_lds(
      (__attribute__((address_space(1))) void*)g,
      (__attribute__((address_space(3))) void*)l, 16, 0, 0);
}

__device__ __forceinline__ unsigned short f2bf_bits(float f) {
  union { bf16 h; unsigned short u; } cv;
  cv.h = __float2bfloat16(f);
  return cv.u;
}
__device__ __forceinline__ uint32_t pk_bf2(float a, float b) {
  return (uint32_t)f2bf_bits(a) | ((uint32_t)f2bf_bits(b) << 16);
}

// 1/sqrt(64) * log2(e), folded into Q at the QKV-GEMM epilogue
#define QSC 0.18033688011111793f

// ---------------- prep kernels ----------------

__global__ void convert_x_k(const float* __restrict__ x, bf16* __restrict__ xb) {
  const int i = blockIdx.x * blockDim.x + threadIdx.x;
  const float4 v = reinterpret_cast<const float4*>(x)[i];
  ushort4 o;
  o.x = f2bf_bits(v.x); o.y = f2bf_bits(v.y);
  o.z = f2bf_bits(v.z); o.w = f2bf_bits(v.w);
  reinterpret_cast<ushort4*>(xb)[i] = o;
}

__global__ void transpose_w_k(const float* __restrict__ Wq, const float* __restrict__ Wk,
                              const float* __restrict__ Wv, const float* __restrict__ Wo,
                              bf16* __restrict__ wcat, bf16* __restrict__ wot) {
  __shared__ float tile[64][65];
  const int mat = blockIdx.z;
  const float* W = (mat == 0) ? Wq : (mat == 1) ? Wk : (mat == 2) ? Wv : Wo;
  bf16* dst = (mat < 3) ? (wcat + (size_t)mat * 1024 * 1024) : wot;
  const int n0 = blockIdx.x * 64, k0 = blockIdx.y * 64;
  const int tr = threadIdx.x >> 6, tc = threadIdx.x & 63;
#pragma unroll
  for (int it = 0; it < 16; ++it)
    tile[it * 4 + tr][tc] = W[(size_t)(k0 + it * 4 + tr) * 1024 + n0 + tc];
  __syncthreads();
#pragma unroll
  for (int it = 0; it < 16; ++it) {
    const int n = n0 + it * 4 + tr;
    dst[(size_t)n * 1024 + k0 + tc] = __float2bfloat16(tile[tc][it * 4 + tr]);
  }
}

__global__ void build_bias_k(const float* __restrict__ bq, const float* __restrict__ bk,
                             const float* __restrict__ bv, float* __restrict__ bcat) {
  const int i = blockIdx.x * 256 + threadIdx.x;
  if (i < 3072)
    bcat[i] = (i < 1024) ? bq[i] : (i < 2048) ? bk[i - 1024] : bv[i - 2048];
}

// ---------------- QKV GEMM: 256x256, BK=64, 8-phase schedule (m201 port) ------
// 8 waves (2M x 4N), per-wave C = 128x64 = acc[8][4] of 16x16x32 frags.
// LDS 128KB = 2 dbuf x {A0,A1,B0,B1} x 16KB (each = 128 rows x 64 cols bf16).
// st_16x32 swizzle: LDS byte ^= ((byte>>9)&1)<<5, realized as inverse-swizzled
// global SOURCE granule + linear gload_lds dest + XOR on ds_read address.
// Per K-tile (4 phases, one C-quadrant each, K=64):
//  P1: read A(qm0)8+B(qn0)4 | stage B1(t+1) | bar | lgkm0 | 16 MFMA (0,0) | bar
//  P2: read B(qn1)4         | stage A1(t+1) | bar | lgkm0 | 16 MFMA (0,1) | bar
//  P3: read A(qm1)8         | stage B0(t+2) | bar | lgkm0 | 16 MFMA (1,1) | bar
//  P4: (no reads)           | stage A0(t+2) | bar |         16 MFMA (1,0) | vmcnt(4) bar
// Region safety: B(t) dead after P2, A(t) dead after P3; staged data first read
// >=4 phases later, guarded by the counted vmcnt(4) at each block end.
__global__ __launch_bounds__(512, 2) void gemm8ph_k(
    const bf16* __restrict__ A, const bf16* __restrict__ Bt,
    const float* __restrict__ bias,
    bf16* __restrict__ qb, bf16* __restrict__ kb, bf16* __restrict__ vtb)
{
  constexpr int NTILE = 12;                 // 3072 / 256
  __shared__ bf16 smem[65536];              // 128 KB
  const int t = threadIdx.x;
  const int lane = t & 63, w = t >> 6;
  const int g = lane >> 4, r = lane & 15;
  const int wm = w >> 2, wn = w & 3;

  // bijective XCD chunking: 192 wg = 8 xcd * 24
  const int dd_ = blockIdx.x;
  const int wg = (dd_ & 7) * 24 + (dd_ >> 3);
  const int m0 = (wg / NTILE) * 256, n0 = (wg % NTILE) * 256;

  // staging: load i covers 16B-granule G = i*512 + t of a 16KB half-tile
  // [128 rows x 64 cols]; source col-granule inverse-swizzled.
  const int G0 = t, G1 = 512 + t;
  const int vo0 = (G0 >> 3) * 1024 + (((G0 & 7) ^ ((G0 >> 4) & 2)) << 3);
  const int vo1 = (G1 >> 3) * 1024 + (((G1 & 7) ^ ((G1 >> 4) & 2)) << 3);

  // region offsets (bytes within a 64KB dbuf)
  constexpr int OFF_A0 = 0, OFF_A1 = 16384, OFF_B0 = 32768, OFF_B1 = 49152;

  auto STG = [&](const bf16* base, int rowbase, int tt, int roff) {
    if (tt < 16) {
      const bf16* s = base + (size_t)rowbase * 1024 + tt * 64;
      char* dst = (char*)smem + (tt & 1) * 65536 + roff + w * 1024;
      lds_async16(s + vo0, dst);
      lds_async16(s + vo1, dst + 8192);
    }
  };

  // ds_read swizzled per-thread base: row r (within 16), K-granule g
  const int p0 = r * 128 + ((g * 16) ^ ((r & 4) << 3));
  const int sBaseA = wm * 16384 + p0;
  const int sBaseB = 32768 + (wn >> 1) * 16384 + (wn & 1) * 8192 + p0;

  f32x4v acc[8][4] = {};
  bf16x8v af[4][2], bf0[2][2], bf1[2][2];

  // prologue: tile0 {A0,A1,B0,B1}, then B0(1), A0(1); vmcnt(4) -> tile0 landed
  STG(A,  m0,       0, OFF_A0);
  STG(A,  m0 + 128, 0, OFF_A1);
  STG(Bt, n0,       0, OFF_B0);
  STG(Bt, n0 + 128, 0, OFF_B1);
  STG(Bt, n0,       1, OFF_B0);
  STG(A,  m0,       1, OFF_A0);
  asm volatile("s_waitcnt vmcnt(4)" ::: "memory");
  __builtin_amdgcn_s_barrier();

  for (int b = 0; b < 16; ++b) {
    const int d = (b & 1) << 16;
    const char* sm = (const char*)smem;

    // ---- P1: quadrant (qm0, qn0) ----
#pragma unroll
    for (int m = 0; m < 4; ++m)
#pragma unroll
      for (int ks = 0; ks < 2; ++ks)
        af[m][ks] = *(const bf16x8v*)(sm + d + sBaseA + m * 2048 + ks * 64);
#pragma unroll
    for (int n = 0; n < 2; ++n)
#pragma unroll
      for (int ks = 0; ks < 2; ++ks)
        bf0[n][ks] = *(const bf16x8v*)(sm + d + sBaseB + n * 2048 + ks * 64);
    STG(Bt, n0 + 128, b + 1, OFF_B1);
    __builtin_amdgcn_s_barrier();
    asm volatile("s_waitcnt lgkmcnt(0)" ::: "memory");
    __builtin_amdgcn_sched_barrier(0);
    __builtin_amdgcn_s_setprio(1);
#pragma unroll
    for (int m = 0; m < 4; ++m)
#pragma unroll
      for (int n = 0; n < 2; ++n) {
        acc[m][n] = mfma16x16x32(af[m][0], bf0[n][0], acc[m][n]);
        acc[m][n] = mfma16x16x32(af[m][1], bf0[n][1], acc[m][n]);
      }
    __builtin_amdgcn_s_setprio(0);
    __builtin_amdgcn_s_barrier();

    // ---- P2: quadrant (qm0, qn1) ----
#pragma unroll
    for (int n = 0; n < 2; ++n)
#pragma unroll
      for (int ks = 0; ks < 2; ++ks)
        bf1[n][ks] = *(const bf16x8v*)(sm + d + sBaseB + 4096 + n * 2048 + ks * 64);
    STG(A, m0 + 128, b + 1, OFF_A1);
    __builtin_amdgcn_s_barrier();
    asm volatile("s_waitcnt lgkmcnt(0)" ::: "memory");
    __builtin_amdgcn_sched_barrier(0);
    __builtin_amdgcn_s_setprio(1);
#pragma unroll
    for (int m = 0; m < 4; ++m)
#pragma unroll
      for (int n = 0; n < 2; ++n) {
        acc[m][2 + n] = mfma16x16x32(af[m][0], bf1[n][0], acc[m][2 + n]);
        acc[m][2 + n] = mfma16x16x32(af[m][1], bf1[n][1], acc[m][2 + n]);
      }
    __builtin_amdgcn_s_setprio(0);
    __builtin_amdgcn_s_barrier();

    // ---- P3: quadrant (qm1, qn1) ----
#pragma unroll
    for (int m = 0; m < 4; ++m)
#pragma unroll
      for (int ks = 0; ks < 2; ++ks)
        af[m][ks] = *(const bf16x8v*)(sm + d + sBaseA + 8192 + m * 2048 + ks * 64);
    STG(Bt, n0, b + 2, OFF_B0);
    __builtin_amdgcn_s_barrier();
    asm volatile("s_waitcnt lgkmcnt(0)" ::: "memory");
    __builtin_amdgcn_sched_barrier(0);
    __builtin_amdgcn_s_setprio(1);
#pragma unroll
    for (int m = 0; m < 4; ++m)
#pragma unroll
      for (int n = 0; n < 2; ++n) {
        acc[4 + m][2 + n] = mfma16x16x32(af[m][0], bf1[n][0], acc[4 + m][2 + n]);
        acc[4 + m][2 + n] = mfma16x16x32(af[m][1], bf1[n][1], acc[4 + m][2 + n]);
      }
    __builtin_amdgcn_s_setprio(0);
    __builtin_amdgcn_s_barrier();

    // ---- P4: quadrant (qm1, qn0), no new reads ----
    STG(A, m0, b + 2, OFF_A0);
    __builtin_amdgcn_s_barrier();
    __builtin_amdgcn_s_setprio(1);
#pragma unroll
    for (int m = 0; m < 4; ++m)
#pragma unroll
      for (int n = 0; n < 2; ++n) {
        acc[4 + m][n] = mfma16x16x32(af[m][0], bf0[n][0], acc[4 + m][n]);
        acc[4 + m][n] = mfma16x16x32(af[m][1], bf0[n][1], acc[4 + m][n]);
      }
    __builtin_amdgcn_s_setprio(0);
    if (b < 14) asm volatile("s_waitcnt vmcnt(4)" ::: "memory");
    else        asm volatile("s_waitcnt vmcnt(0)" ::: "memory");
    __builtin_amdgcn_s_barrier();
  }

  // epilogue: scatter q/k/vt with bias (+QSC fold into q)
#pragma unroll
  for (int n = 0; n < 4; ++n) {
    const int gcol = n0 + wn * 64 + n * 16 + r;
    const float bv_ = bias[gcol];
    const int mat = gcol >> 10;          // block-uniform
    const int dcol = gcol & 1023;
    const int hh = dcol >> 6, dk = dcol & 63;
#pragma unroll
    for (int m = 0; m < 8; ++m) {
#pragma unroll
      for (int v = 0; v < 4; ++v) {
        const int grow = m0 + wm * 128 + m * 16 + g * 4 + v;
        const int b_ = grow >> 11, s = grow & 2047;
        const float val = acc[m][n][v] + bv_;
        const size_t bh = (size_t)(b_ * 16 + hh);
        if (mat == 0)      qb[(bh * 2048 + s) * 64 + dk] = __float2bfloat16(val * QSC);
        else if (mat == 1) kb[(bh * 2048 + s) * 64 + dk] = __float2bfloat16(val);
        else               vtb[(bh * 64 + dk) * 2048 + s] = __float2bfloat16(val);
      }
    }
  }
}

// ---------------- out-proj GEMM (m97-style 128^2, unchanged) ----------------
__global__ __launch_bounds__(256, 2) void gemm_k(
    const bf16* __restrict__ A, const bf16* __restrict__ Bt,
    const float* __restrict__ bias, float* __restrict__ outf)
{
  constexpr int K = 1024;
  __shared__ bf16 As[128 * 32];
  __shared__ bf16 Bs[128 * 32];
  const int t = threadIdx.x;
  const int lane = t & 63, w = t >> 6;
  const int g = lane >> 4, r = lane & 15;
  const int wr = w >> 1, wc = w & 1;
  const int m0 = blockIdx.x * 128, n0 = blockIdx.y * 128;

  const int srow = w * 16 + (lane >> 2);
  const int skoff = (lane & 3) * 8;
  const bf16* aSrc0 = A + (size_t)(m0 + srow) * K + skoff;
  const bf16* aSrc1 = aSrc0 + (size_t)64 * K;
  const bf16* bSrc0 = Bt + (size_t)(n0 + srow) * K + skoff;
  const bf16* bSrc1 = bSrc0 + (size_t)64 * K;
  bf16* aDst0 = As + w * 512;
  bf16* aDst1 = As + 2048 + w * 512;
  bf16* bDst0 = Bs + w * 512;
  bf16* bDst1 = Bs + 2048 + w * 512;

  f32x4v acc[4][4] = {};

  for (int kt = 0; kt < K; kt += 32) {
    lds_async16(aSrc0 + kt, aDst0);
    lds_async16(aSrc1 + kt, aDst1);
    lds_async16(bSrc0 + kt, bDst0);
    lds_async16(bSrc1 + kt, bDst1);
    __syncthreads();
    bf16x8v af[4], bfr[4];
#pragma unroll
    for (int m = 0; m < 4; ++m)
      af[m] = *reinterpret_cast<const bf16x8v*>(&As[(wr * 64 + m * 16 + r) * 32 + g * 8]);
#pragma unroll
    for (int n = 0; n < 4; ++n)
      bfr[n] = *reinterpret_cast<const bf16x8v*>(&Bs[(wc * 64 + n * 16 + r) * 32 + g * 8]);
#pragma unroll
    for (int m = 0; m < 4; ++m)
#pragma unroll
      for (int n = 0; n < 4; ++n)
        acc[m][n] = mfma16x16x32(af[m], bfr[n], acc[m][n]);
    __syncthreads();
  }

#pragma unroll
  for (int n = 0; n < 4; ++n) {
    const int gcol = n0 + wc * 64 + n * 16 + r;
    const float bv_ = bias[gcol];
#pragma unroll
    for (int m = 0; m < 4; ++m) {
#pragma unroll
      for (int v = 0; v < 4; ++v) {
        const int grow = m0 + wr * 64 + m * 16 + g * 4 + v;
        outf[(size_t)grow * 1024 + gcol] = acc[m][n][v] + bv_;
      }
    }
  }
}

// ---------------- sliding-window attention (unchanged from R4) ----------------
__global__ __launch_bounds__(64) void attn_k(
    const bf16* __restrict__ qb, const bf16* __restrict__ kb_,
    const bf16* __restrict__ vtb, bf16* __restrict__ aout)
{
  constexpr int S = 2048;
  const int lane = threadIdx.x & 63;
  const int hi = lane >> 5, l31 = lane & 31;
  const int d_ = blockIdx.x;
  const int xcd = d_ & 7, slot = d_ >> 3;
  const int bh_i = xcd * 4 + (slot >> 6);
  const int q0 = (slot & 63) * 32;
  const int b = bh_i >> 4, h = bh_i & 15;
  const size_t bh = (size_t)b * 16 + h;
  const bf16* qp = qb + bh * (size_t)(S * 64);
  const bf16* kp = kb_ + bh * (size_t)(S * 64);
  const bf16* vp = vtb + bh * (size_t)(64 * S);

  bf16x8v qf[4];
#pragma unroll
  for (int i = 0; i < 4; ++i)
    qf[i] = *reinterpret_cast<const bf16x8v*>(&qp[(size_t)(q0 + l31) * 64 + i * 16 + hi * 8]);

  f32x16v o0 = {}, o1 = {};
  float lrun = 0.f;

  const int jlo = (q0 >= 256) ? (q0 - 256) : 0;
  const int jend = (q0 + 256 <= S - 32) ? (q0 + 256) : (S - 32);
  const int nIter = ((jend - jlo) >> 5) + 1;

  auto LDK = [&](int j, bf16x8v* kf) {
    const bf16* p0 = kp + (size_t)(j + l31) * 64 + hi * 8;
#pragma unroll
    for (int i = 0; i < 4; ++i)
      kf[i] = *reinterpret_cast<const bf16x8v*>(p0 + i * 16);
  };
  auto LDV = [&](int j, bf16x8v* vf) {
#pragma unroll
    for (int db = 0; db < 2; ++db)
#pragma unroll
      for (int kk = 0; kk < 2; ++kk)
        vf[db * 2 + kk] = *reinterpret_cast<const bf16x8v*>(
            &vp[(size_t)(db * 32 + l31) * S + j + kk * 16 + hi * 8]);
  };

  auto STEP = [&](int idx, bf16x8v* kc, bf16x8v* vc, bf16x8v* kn, bf16x8v* vn) {
    const int j = jlo + idx * 32;
    if (idx + 1 < nIter) { LDK(j + 32, kn); LDV(j + 32, vn); }

    f32x16v s = {};
#pragma unroll
    for (int i = 0; i < 4; ++i) s = mfma32x32x16(kc[i], qf[i], s);

    float p[16];
    const bool needMask = ((q0 + 31 - j) > 256) || ((j + 31 - q0) > 256);
    if (needMask) {
      const int base = l31 - 4 * hi + (q0 - j) + 256;
#pragma unroll
      for (int tt = 0; tt < 4; ++tt)
#pragma unroll
        for (int e = 0; e < 4; ++e) {
          const int kk_ = 8 * tt + e;
          const float ev = __builtin_amdgcn_exp2f(s[4 * tt + e]);
          p[4 * tt + e] = ((unsigned)(base - kk_) <= 512u) ? ev : 0.f;
        }
    } else {
#pragma unroll
      for (int i = 0; i < 16; ++i) p[i] = __builtin_amdgcn_exp2f(s[i]);
    }
    lrun += (((p[0] + p[1]) + (p[2] + p[3])) + ((p[4] + p[5]) + (p[6] + p[7]))) +
            (((p[8] + p[9]) + (p[10] + p[11])) + ((p[12] + p[13]) + (p[14] + p[15])));

    uint32_t W00 = pk_bf2(p[0],  p[1]),  W01 = pk_bf2(p[2],  p[3]);
    uint32_t W10 = pk_bf2(p[4],  p[5]),  W11 = pk_bf2(p[6],  p[7]);
    uint32_t W20 = pk_bf2(p[8],  p[9]),  W21 = pk_bf2(p[10], p[11]);
    uint32_t W30 = pk_bf2(p[12], p[13]), W31 = pk_bf2(p[14], p[15]);
    asm volatile("v_permlane32_swap_b32 %0, %1" : "+v"(W00), "+v"(W10));
    asm volatile("v_permlane32_swap_b32 %0, %1" : "+v"(W01), "+v"(W11));
    asm volatile("v_permlane32_swap_b32 %0, %1" : "+v"(W20), "+v"(W30));
    asm volatile("v_permlane32_swap_b32 %0, %1" : "+v"(W21), "+v"(W31));
    union { i32x4v i; bf16x8v hv; } c0, c1;
    c0.i = (i32x4v){(int)W00, (int)W01, (int)W10, (int)W11};
    c1.i = (i32x4v){(int)W20, (int)W21, (int)W30, (int)W31};
    o0 = mfma32x32x16(vc[0], c0.hv, o0);
    o0 = mfma32x32x16(vc[1], c1.hv, o0);
    o1 = mfma32x32x16(vc[2], c0.hv, o1);
    o1 = mfma32x32x16(vc[3], c1.hv, o1);
  };

  bf16x8v ka[4], va[4], kn2[4], vn2[4];
  LDK(jlo, ka); LDV(jlo, va);
  int it = 0;
  while (it + 2 <= nIter) {
    STEP(it, ka, va, kn2, vn2);
    STEP(it + 1, kn2, vn2, ka, va);
    it += 2;
  }
  if (it < nIter) STEP(it, ka, va, kn2, vn2);

  lrun += __shfl_xor(lrun, 32);
  const float inv = 1.0f / lrun;

  const size_t ob = ((size_t)b * S + q0 + l31) * 1024 + h * 64 + hi * 4;
#pragma unroll
  for (int tt = 0; tt < 4; ++tt) {
    uint2 u;
    u.x = pk_bf2(o0[4 * tt] * inv, o0[4 * tt + 1] * inv);
    u.y = pk_bf2(o0[4 * tt + 2] * inv, o0[4 * tt + 3] * inv);
    *reinterpret_cast<uint2*>(&aout[ob + 8 * tt]) = u;
    uint2 v2;
    v2.x = pk_bf2(o1[4 * tt] * inv, o1[4 * tt + 1] * inv);
    v2.y = pk_bf2(o1[4 * tt + 2] * inv, o1[4 * tt + 3] * inv);
    *reinterpret_cast<uint2*>(&aout[ob + 32 + 8 * tt]) = v2;
  }
}

// ---------------- launch ----------------
extern "C" void kernel_launch(void* const* d_in, const int* in_sizes, int n_in,
                              void* d_out, int out_size, void* d_ws, size_t ws_size,
                              hipStream_t stream) {
  (void)in_sizes; (void)n_in; (void)out_size; (void)ws_size;
  const float* x  = (const float*)d_in[0];
  const float* Wq = (const float*)d_in[1];
  const float* bq = (const float*)d_in[2];
  const float* Wk = (const float*)d_in[3];
  const float* bk = (const float*)d_in[4];
  const float* Wv = (const float*)d_in[5];
  const float* bv = (const float*)d_in[6];
  const float* Wo = (const float*)d_in[7];
  const float* bo = (const float*)d_in[8];
  float* out = (float*)d_out;

  char* ws = (char*)d_ws;
  bf16*  xb    = (bf16*)(ws);                    // 8 MB  [4096][1024]
  bf16*  wcat  = (bf16*)(ws + 8388608);          // 6 MB  [3072][1024]
  bf16*  wot   = (bf16*)(ws + 14680064);         // 2 MB  [1024][1024]
  bf16*  qbuf  = (bf16*)(ws + 16777216);         // 8 MB  [B,H,S,64] (pre-scaled)
  bf16*  kbuf  = (bf16*)(ws + 25165824);         // 8 MB  [B,H,S,64]
  bf16*  vtbuf = (bf16*)(ws + 33554432);         // 8 MB  [B,H,64,S]
  bf16*  aoutb = (bf16*)(ws + 41943040);         // 8 MB  [B,S,1024]
  float* bcat  = (float*)(ws + 50331648);        // 12 KB [3072]

  convert_x_k<<<4096, 256, 0, stream>>>(x, xb);
  transpose_w_k<<<dim3(16, 16, 4), 256, 0, stream>>>(Wq, Wk, Wv, Wo, wcat, wot);
  build_bias_k<<<12, 256, 0, stream>>>(bq, bk, bv, bcat);

  gemm8ph_k<<<192, 512, 0, stream>>>(xb, wcat, bcat, qbuf, kbuf, vtbuf);
  attn_k<<<2048, 64, 0, stream>>>(qbuf, kbuf, vtbuf, aoutb);
  gemm_k<<<dim3(32, 8), 256, 0, stream>>>(aoutb, wot, bo, out);
}

// Round 8
// 106.085 us; speedup vs baseline: 1.2791x; 1.2791x over previous
//
#include <hip/hip_runtime.h>
#include <hip/hip_bf16.h>
#include <cstdint>
#include <cstddef>

using bf16 = __hip_bfloat16;
typedef __attribute__((ext_vector_type(8))) short bf16x8v;
typedef __attribute__((ext_vector_type(4))) float f32x4v;
typedef __attribute__((ext_vector_type(16))) float f32x16v;
typedef __attribute__((ext_vector_type(4))) int i32x4v;

__device__ __forceinline__ f32x4v mfma16x16x32(bf16x8v a, bf16x8v b, f32x4v c) {
  return __builtin_amdgcn_mfma_f32_16x16x32_bf16(a, b, c, 0, 0, 0);
}
__device__ __forceinline__ f32x16v mfma32x32x16(bf16x8v a, bf16x8v b, f32x16v c) {
  return __builtin_amdgcn_mfma_f32_32x32x16_bf16(a, b, c, 0, 0, 0);
}

__device__ __forceinline__ void lds_async16(const void* g, void* l) {
  __builtin_amdgcn_global_load_lds(
      (__attribute__((address_space(1))) void*)g,
      (__attribute__((address_space(3))) void*)l, 16, 0, 0);
}

__device__ __forceinline__ unsigned short f2bf_bits(float f) {
  union { bf16 h; unsigned short u; } cv;
  cv.h = __float2bfloat16(f);
  return cv.u;
}
__device__ __forceinline__ uint32_t pk_bf2(float a, float b) {
  return (uint32_t)f2bf_bits(a) | ((uint32_t)f2bf_bits(b) << 16);
}

// 1/sqrt(64) * log2(e), folded into Q at the QKV-GEMM epilogue
#define QSC 0.18033688011111793f

// ---------------- prep kernels ----------------

__global__ void convert_x_k(const float* __restrict__ x, bf16* __restrict__ xb) {
  const int i = blockIdx.x * blockDim.x + threadIdx.x;
  const float4 v = reinterpret_cast<const float4*>(x)[i];
  ushort4 o;
  o.x = f2bf_bits(v.x); o.y = f2bf_bits(v.y);
  o.z = f2bf_bits(v.z); o.w = f2bf_bits(v.w);
  reinterpret_cast<ushort4*>(xb)[i] = o;
}

__global__ void transpose_w_k(const float* __restrict__ Wq, const float* __restrict__ Wk,
                              const float* __restrict__ Wv, const float* __restrict__ Wo,
                              bf16* __restrict__ wcat, bf16* __restrict__ wot) {
  __shared__ float tile[64][65];
  const int mat = blockIdx.z;
  const float* W = (mat == 0) ? Wq : (mat == 1) ? Wk : (mat == 2) ? Wv : Wo;
  bf16* dst = (mat < 3) ? (wcat + (size_t)mat * 1024 * 1024) : wot;
  const int n0 = blockIdx.x * 64, k0 = blockIdx.y * 64;
  const int tr = threadIdx.x >> 6, tc = threadIdx.x & 63;
#pragma unroll
  for (int it = 0; it < 16; ++it)
    tile[it * 4 + tr][tc] = W[(size_t)(k0 + it * 4 + tr) * 1024 + n0 + tc];
  __syncthreads();
#pragma unroll
  for (int it = 0; it < 16; ++it) {
    const int n = n0 + it * 4 + tr;
    dst[(size_t)n * 1024 + k0 + tc] = __float2bfloat16(tile[tc][it * 4 + tr]);
  }
}

__global__ void build_bias_k(const float* __restrict__ bq, const float* __restrict__ bk,
                             const float* __restrict__ bv, float* __restrict__ bcat) {
  const int i = blockIdx.x * 256 + threadIdx.x;
  if (i < 3072)
    bcat[i] = (i < 1024) ? bq[i] : (i < 2048) ? bk[i - 1024] : bv[i - 2048];
}

// ---------------- GEMM: C[M,N] = A[M,K] @ Bt[N,K]^T (+bias) ----------------
// m97 structure, BK=64 (16 iters instead of 32 -> half the barrier drains).
// 128x128 tile, 4 waves (2x2), per-wave 64x64 = 4x4 frags of 16x16x32, 2 ks.
// LDS 32KB single-buffer; [128 rows x 64 cols] bf16 = 128B rows.
// Bank swizzle (both-sides, rule #21): 16B-granule within a row permuted by
// gr ^= (row&7); inverse applied to the per-lane GLOBAL source, gload_lds dest
// linear, XOR on the ds_read address. Each b128 read then spans all 8 granules
// (32 banks) uniformly -> conflict-free.
// EPI=0: N=3072, scatter q/k [B,H,S,64] + Vt [B,H,64,S] with bias (+QSC on q).
// EPI=1: N=1024, f32 row-major + bias.
template <int EPI>
__global__ __launch_bounds__(256, 3) void gemm_k(
    const bf16* __restrict__ A, const bf16* __restrict__ Bt,
    const float* __restrict__ bias,
    bf16* __restrict__ qb, bf16* __restrict__ kb, bf16* __restrict__ vtb,
    float* __restrict__ outf)
{
  constexpr int K = 1024;
  __shared__ bf16 As[128 * 64];   // 16 KB
  __shared__ bf16 Bs[128 * 64];   // 16 KB
  const int t = threadIdx.x;
  const int lane = t & 63, w = t >> 6;
  const int g = lane >> 4, r = lane & 15;
  const int wr = w >> 1, wc = w & 1;
  const int m0 = blockIdx.x * 128, n0 = blockIdx.y * 128;

  // staging: granule G = t + 256*i (i<4) of each 1024-granule region.
  // dest linear (G*16B); source granule = (G&7) ^ (row&7), row = G>>3.
  const bf16* aS[4];
  const bf16* bS[4];
  bf16* aD[4];
  bf16* bD[4];
#pragma unroll
  for (int i = 0; i < 4; ++i) {
    const int G = t + 256 * i;
    const int row = G >> 3, gd = G & 7;
    const int col = ((gd ^ (row & 7)) << 3);   // elems
    aS[i] = A + (size_t)(m0 + row) * K + col;
    bS[i] = Bt + (size_t)(n0 + row) * K + col;
    aD[i] = As + w * 512 + i * 2048;           // uniform per wave; HW adds lane*16B
    bD[i] = Bs + w * 512 + i * 2048;
  }

  f32x4v acc[4][4] = {};

  for (int kt = 0; kt < 16; ++kt) {
    const int ko = kt * 64;
#pragma unroll
    for (int i = 0; i < 4; ++i) {
      lds_async16(aS[i] + ko, aD[i]);
      lds_async16(bS[i] + ko, bD[i]);
    }
    __syncthreads();

#pragma unroll
    for (int ks = 0; ks < 2; ++ks) {
      const int csw = ((ks * 4 + g) ^ (r & 7)) << 4;  // swizzled 16B granule
      bf16x8v af[4];
#pragma unroll
      for (int m = 0; m < 4; ++m)
        af[m] = *reinterpret_cast<const bf16x8v*>(
            (const char*)As + (wr * 64 + m * 16 + r) * 128 + csw);
#pragma unroll
      for (int n = 0; n < 4; ++n) {
        const bf16x8v bf_ = *reinterpret_cast<const bf16x8v*>(
            (const char*)Bs + (wc * 64 + n * 16 + r) * 128 + csw);
#pragma unroll
        for (int m = 0; m < 4; ++m)
          acc[m][n] = mfma16x16x32(af[m], bf_, acc[m][n]);
      }
    }
    __syncthreads();
  }

  // epilogue: C[row][col], col = lane&15, row = (lane>>4)*4 + v  [m89/m91]
#pragma unroll
  for (int n = 0; n < 4; ++n) {
    const int gcol = n0 + wc * 64 + n * 16 + r;
    const float bv_ = bias[gcol];
    if (EPI == 0) {
      const int mat = gcol >> 10;
      const int d = gcol & 1023;
      const int hh = d >> 6, dk = d & 63;
#pragma unroll
      for (int m = 0; m < 4; ++m) {
#pragma unroll
        for (int v = 0; v < 4; ++v) {
          const int grow = m0 + wr * 64 + m * 16 + g * 4 + v;
          const int b = grow >> 11, s = grow & 2047;
          const float val = acc[m][n][v] + bv_;
          const size_t bh = (size_t)(b * 16 + hh);
          if (mat == 0)      qb[(bh * 2048 + s) * 64 + dk] = __float2bfloat16(val * QSC);
          else if (mat == 1) kb[(bh * 2048 + s) * 64 + dk] = __float2bfloat16(val);
          else               vtb[(bh * 64 + dk) * 2048 + s] = __float2bfloat16(val);
        }
      }
    } else {
#pragma unroll
      for (int m = 0; m < 4; ++m) {
#pragma unroll
        for (int v = 0; v < 4; ++v) {
          const int grow = m0 + wr * 64 + m * 16 + g * 4 + v;
          outf[(size_t)grow * 1024 + gcol] = acc[m][n][v] + bv_;
        }
      }
    }
  }
}

// ---------------- sliding-window attention (unchanged from R4) ----------------
__global__ __launch_bounds__(64) void attn_k(
    const bf16* __restrict__ qb, const bf16* __restrict__ kb_,
    const bf16* __restrict__ vtb, bf16* __restrict__ aout)
{
  constexpr int S = 2048;
  const int lane = threadIdx.x & 63;
  const int hi = lane >> 5, l31 = lane & 31;
  const int d_ = blockIdx.x;
  const int xcd = d_ & 7, slot = d_ >> 3;
  const int bh_i = xcd * 4 + (slot >> 6);
  const int q0 = (slot & 63) * 32;
  const int b = bh_i >> 4, h = bh_i & 15;
  const size_t bh = (size_t)b * 16 + h;
  const bf16* qp = qb + bh * (size_t)(S * 64);
  const bf16* kp = kb_ + bh * (size_t)(S * 64);
  const bf16* vp = vtb + bh * (size_t)(64 * S);

  bf16x8v qf[4];
#pragma unroll
  for (int i = 0; i < 4; ++i)
    qf[i] = *reinterpret_cast<const bf16x8v*>(&qp[(size_t)(q0 + l31) * 64 + i * 16 + hi * 8]);

  f32x16v o0 = {}, o1 = {};
  float lrun = 0.f;

  const int jlo = (q0 >= 256) ? (q0 - 256) : 0;
  const int jend = (q0 + 256 <= S - 32) ? (q0 + 256) : (S - 32);
  const int nIter = ((jend - jlo) >> 5) + 1;

  auto LDK = [&](int j, bf16x8v* kf) {
    const bf16* p0 = kp + (size_t)(j + l31) * 64 + hi * 8;
#pragma unroll
    for (int i = 0; i < 4; ++i)
      kf[i] = *reinterpret_cast<const bf16x8v*>(p0 + i * 16);
  };
  auto LDV = [&](int j, bf16x8v* vf) {
#pragma unroll
    for (int db = 0; db < 2; ++db)
#pragma unroll
      for (int kk = 0; kk < 2; ++kk)
        vf[db * 2 + kk] = *reinterpret_cast<const bf16x8v*>(
            &vp[(size_t)(db * 32 + l31) * S + j + kk * 16 + hi * 8]);
  };

  auto STEP = [&](int idx, bf16x8v* kc, bf16x8v* vc, bf16x8v* kn, bf16x8v* vn) {
    const int j = jlo + idx * 32;
    if (idx + 1 < nIter) { LDK(j + 32, kn); LDV(j + 32, vn); }

    f32x16v s = {};
#pragma unroll
    for (int i = 0; i < 4; ++i) s = mfma32x32x16(kc[i], qf[i], s);

    float p[16];
    const bool needMask = ((q0 + 31 - j) > 256) || ((j + 31 - q0) > 256);
    if (needMask) {
      const int base = l31 - 4 * hi + (q0 - j) + 256;
#pragma unroll
      for (int tt = 0; tt < 4; ++tt)
#pragma unroll
        for (int e = 0; e < 4; ++e) {
          const int kk_ = 8 * tt + e;
          const float ev = __builtin_amdgcn_exp2f(s[4 * tt + e]);
          p[4 * tt + e] = ((unsigned)(base - kk_) <= 512u) ? ev : 0.f;
        }
    } else {
#pragma unroll
      for (int i = 0; i < 16; ++i) p[i] = __builtin_amdgcn_exp2f(s[i]);
    }
    lrun += (((p[0] + p[1]) + (p[2] + p[3])) + ((p[4] + p[5]) + (p[6] + p[7]))) +
            (((p[8] + p[9]) + (p[10] + p[11])) + ((p[12] + p[13]) + (p[14] + p[15])));

    uint32_t W00 = pk_bf2(p[0],  p[1]),  W01 = pk_bf2(p[2],  p[3]);
    uint32_t W10 = pk_bf2(p[4],  p[5]),  W11 = pk_bf2(p[6],  p[7]);
    uint32_t W20 = pk_bf2(p[8],  p[9]),  W21 = pk_bf2(p[10], p[11]);
    uint32_t W30 = pk_bf2(p[12], p[13]), W31 = pk_bf2(p[14], p[15]);
    asm volatile("v_permlane32_swap_b32 %0, %1" : "+v"(W00), "+v"(W10));
    asm volatile("v_permlane32_swap_b32 %0, %1" : "+v"(W01), "+v"(W11));
    asm volatile("v_permlane32_swap_b32 %0, %1" : "+v"(W20), "+v"(W30));
    asm volatile("v_permlane32_swap_b32 %0, %1" : "+v"(W21), "+v"(W31));
    union { i32x4v i; bf16x8v hv; } c0, c1;
    c0.i = (i32x4v){(int)W00, (int)W01, (int)W10, (int)W11};
    c1.i = (i32x4v){(int)W20, (int)W21, (int)W30, (int)W31};
    o0 = mfma32x32x16(vc[0], c0.hv, o0);
    o0 = mfma32x32x16(vc[1], c1.hv, o0);
    o1 = mfma32x32x16(vc[2], c0.hv, o1);
    o1 = mfma32x32x16(vc[3], c1.hv, o1);
  };

  bf16x8v ka[4], va[4], kn2[4], vn2[4];
  LDK(jlo, ka); LDV(jlo, va);
  int it = 0;
  while (it + 2 <= nIter) {
    STEP(it, ka, va, kn2, vn2);
    STEP(it + 1, kn2, vn2, ka, va);
    it += 2;
  }
  if (it < nIter) STEP(it, ka, va, kn2, vn2);

  lrun += __shfl_xor(lrun, 32);
  const float inv = 1.0f / lrun;

  const size_t ob = ((size_t)b * S + q0 + l31) * 1024 + h * 64 + hi * 4;
#pragma unroll
  for (int tt = 0; tt < 4; ++tt) {
    uint2 u;
    u.x = pk_bf2(o0[4 * tt] * inv, o0[4 * tt + 1] * inv);
    u.y = pk_bf2(o0[4 * tt + 2] * inv, o0[4 * tt + 3] * inv);
    *reinterpret_cast<uint2*>(&aout[ob + 8 * tt]) = u;
    uint2 v2;
    v2.x = pk_bf2(o1[4 * tt] * inv, o1[4 * tt + 1] * inv);
    v2.y = pk_bf2(o1[4 * tt + 2] * inv, o1[4 * tt + 3] * inv);
    *reinterpret_cast<uint2*>(&aout[ob + 32 + 8 * tt]) = v2;
  }
}

// ---------------- launch ----------------
extern "C" void kernel_launch(void* const* d_in, const int* in_sizes, int n_in,
                              void* d_out, int out_size, void* d_ws, size_t ws_size,
                              hipStream_t stream) {
  (void)in_sizes; (void)n_in; (void)out_size; (void)ws_size;
  const float* x  = (const float*)d_in[0];
  const float* Wq = (const float*)d_in[1];
  const float* bq = (const float*)d_in[2];
  const float* Wk = (const float*)d_in[3];
  const float* bk = (const float*)d_in[4];
  const float* Wv = (const float*)d_in[5];
  const float* bv = (const float*)d_in[6];
  const float* Wo = (const float*)d_in[7];
  const float* bo = (const float*)d_in[8];
  float* out = (float*)d_out;

  char* ws = (char*)d_ws;
  bf16*  xb    = (bf16*)(ws);                    // 8 MB  [4096][1024]
  bf16*  wcat  = (bf16*)(ws + 8388608);          // 6 MB  [3072][1024]
  bf16*  wot   = (bf16*)(ws + 14680064);         // 2 MB  [1024][1024]
  bf16*  qbuf  = (bf16*)(ws + 16777216);         // 8 MB  [B,H,S,64] (pre-scaled)
  bf16*  kbuf  = (bf16*)(ws + 25165824);         // 8 MB  [B,H,S,64]
  bf16*  vtbuf = (bf16*)(ws + 33554432);         // 8 MB  [B,H,64,S]
  bf16*  aoutb = (bf16*)(ws + 41943040);         // 8 MB  [B,S,1024]
  float* bcat  = (float*)(ws + 50331648);        // 12 KB [3072]

  convert_x_k<<<4096, 256, 0, stream>>>(x, xb);
  transpose_w_k<<<dim3(16, 16, 4), 256, 0, stream>>>(Wq, Wk, Wv, Wo, wcat, wot);
  build_bias_k<<<12, 256, 0, stream>>>(bq, bk, bv, bcat);

  gemm_k<0><<<dim3(32, 24), 256, 0, stream>>>(xb, wcat, bcat, qbuf, kbuf, vtbuf, nullptr);
  attn_k<<<2048, 64, 0, stream>>>(qbuf, kbuf, vtbuf, aoutb);
  gemm_k<1><<<dim3(32, 8), 256, 0, stream>>>(aoutb, wot, bo, nullptr, nullptr, nullptr, out);
}